// Round 1
// baseline (36.432 us; speedup 1.0000x reference)
//
#include <hip/hip_runtime.h>
#include <hip/hip_bf16.h>

#define D_FEAT 128

// K1: per-node projection p_u[n] = h[n] . W[0:128], p_v[n] = h[n] . W[128:256]
// One wave (64 lanes) per node; lane i loads h[n][2i], h[n][2i+1] (coalesced).
__global__ void proj_kernel(const float* __restrict__ h,
                            const float* __restrict__ W,
                            float* __restrict__ pu,
                            float* __restrict__ pv,
                            int n_nodes) {
    int gtid = blockIdx.x * blockDim.x + threadIdx.x;
    int node = gtid >> 6;          // wave id
    int lane = threadIdx.x & 63;
    if (node >= n_nodes) return;

    const float2 hv = *reinterpret_cast<const float2*>(h + (size_t)node * D_FEAT + lane * 2);
    const float2 wu = *reinterpret_cast<const float2*>(W + lane * 2);
    const float2 wv = *reinterpret_cast<const float2*>(W + D_FEAT + lane * 2);

    float su = hv.x * wu.x + hv.y * wu.y;
    float sv = hv.x * wv.x + hv.y * wv.y;

    #pragma unroll
    for (int off = 32; off > 0; off >>= 1) {
        su += __shfl_xor(su, off, 64);
        sv += __shfl_xor(sv, off, 64);
    }
    if (lane == 0) {
        pu[node] = su;
        pv[node] = sv;
    }
}

// K2: score[e] = pu[src[e]] + pv[dst[e]] + b; write raw score to out;
// block-level min/max partials to pmin/pmax.
__global__ void score_kernel(const int* __restrict__ src,
                             const int* __restrict__ dst,
                             const float* __restrict__ pu,
                             const float* __restrict__ pv,
                             const float* __restrict__ bptr,
                             float* __restrict__ out,
                             float* __restrict__ pmin,
                             float* __restrict__ pmax,
                             int n_edges) {
    int i = blockIdx.x * blockDim.x + threadIdx.x;
    float vmin =  3.4028235e38f;
    float vmax = -3.4028235e38f;
    if (i < n_edges) {
        float s = pu[src[i]] + pv[dst[i]] + bptr[0];
        out[i] = s;
        vmin = s;
        vmax = s;
    }
    #pragma unroll
    for (int off = 32; off > 0; off >>= 1) {
        vmin = fminf(vmin, __shfl_xor(vmin, off, 64));
        vmax = fmaxf(vmax, __shfl_xor(vmax, off, 64));
    }
    __shared__ float smin[4], smax[4];
    int w = threadIdx.x >> 6;
    if ((threadIdx.x & 63) == 0) { smin[w] = vmin; smax[w] = vmax; }
    __syncthreads();
    if (threadIdx.x == 0) {
        float a = smin[0], b = smax[0];
        #pragma unroll
        for (int k = 1; k < 4; ++k) { a = fminf(a, smin[k]); b = fmaxf(b, smax[k]); }
        pmin[blockIdx.x] = a;
        pmax[blockIdx.x] = b;
    }
}

// K3: single block reduces the per-block partials -> g[0]=min, g[1]=max
__global__ void minmax_reduce_kernel(const float* __restrict__ pmin,
                                     const float* __restrict__ pmax,
                                     float* __restrict__ g,
                                     int n) {
    float vmin =  3.4028235e38f;
    float vmax = -3.4028235e38f;
    for (int i = threadIdx.x; i < n; i += blockDim.x) {
        vmin = fminf(vmin, pmin[i]);
        vmax = fmaxf(vmax, pmax[i]);
    }
    #pragma unroll
    for (int off = 32; off > 0; off >>= 1) {
        vmin = fminf(vmin, __shfl_xor(vmin, off, 64));
        vmax = fmaxf(vmax, __shfl_xor(vmax, off, 64));
    }
    __shared__ float smin[16], smax[16];
    int w = threadIdx.x >> 6;
    if ((threadIdx.x & 63) == 0) { smin[w] = vmin; smax[w] = vmax; }
    __syncthreads();
    if (threadIdx.x == 0) {
        int nw = blockDim.x >> 6;
        float a = smin[0], b = smax[0];
        for (int k = 1; k < nw; ++k) { a = fminf(a, smin[k]); b = fmaxf(b, smax[k]); }
        g[0] = a;
        g[1] = b;
    }
}

// K4: in-place normalize out[i] = (out[i]-min)/(max-min), float4 vectorized.
__global__ void norm_kernel(float* __restrict__ out,
                            const float* __restrict__ g,
                            int n4) {
    int i = blockIdx.x * blockDim.x + threadIdx.x;
    if (i >= n4) return;
    float mn = g[0];
    float inv = 1.0f / (g[1] - mn);
    float4 v = reinterpret_cast<float4*>(out)[i];
    v.x = (v.x - mn) * inv;
    v.y = (v.y - mn) * inv;
    v.z = (v.z - mn) * inv;
    v.w = (v.w - mn) * inv;
    reinterpret_cast<float4*>(out)[i] = v;
}

extern "C" void kernel_launch(void* const* d_in, const int* in_sizes, int n_in,
                              void* d_out, int out_size, void* d_ws, size_t ws_size,
                              hipStream_t stream) {
    const float* h   = (const float*)d_in[0];
    const int*   src = (const int*)d_in[1];
    const int*   dst = (const int*)d_in[2];
    const float* W   = (const float*)d_in[3];
    const float* b   = (const float*)d_in[4];
    float* out = (float*)d_out;

    const int n_nodes = in_sizes[0] / D_FEAT;
    const int n_edges = in_sizes[1];

    // workspace layout (floats)
    float* ws  = (float*)d_ws;
    float* pu  = ws;                       // n_nodes
    float* pv  = ws + n_nodes;             // n_nodes
    float* pmin = ws + 2 * n_nodes;        // nblk2
    const int nblk2 = (n_edges + 255) / 256;
    float* pmax = pmin + nblk2;            // nblk2
    float* g    = pmax + nblk2;            // 2

    // K1: 1 wave/node, 4 waves/block
    {
        int waves_per_block = 4;
        int blocks = (n_nodes + waves_per_block - 1) / waves_per_block;
        proj_kernel<<<blocks, 256, 0, stream>>>(h, W, pu, pv, n_nodes);
    }
    // K2
    score_kernel<<<nblk2, 256, 0, stream>>>(src, dst, pu, pv, b, out, pmin, pmax, n_edges);
    // K3
    minmax_reduce_kernel<<<1, 1024, 0, stream>>>(pmin, pmax, g, nblk2);
    // K4 (n_edges divisible by 4: 800000 % 4 == 0)
    {
        int n4 = n_edges / 4;
        int blocks = (n4 + 255) / 256;
        norm_kernel<<<blocks, 256, 0, stream>>>(out, g, n4);
    }
}